// Round 3
// baseline (267.096 us; speedup 1.0000x reference)
//
#include <hip/hip_runtime.h>
#include <hip/hip_bf16.h>

#define DIN   2048
#define DOUT  2048
#define NP    16
#define TPW   8   // tokens per wave

// ws layout (byte offsets)
#define HDR_OFF   0
#define WK4_OFF   16
#define WV4_OFF   (WK4_OFF + 32768)            // 32784
#define Q2_OFF    (WV4_OFF + 32768)            // 65552 (16B aligned)

static __device__ __forceinline__ int dot4(unsigned a, unsigned b, int c) {
#if defined(__has_builtin) && __has_builtin(__builtin_amdgcn_sdot4)
  return __builtin_amdgcn_sdot4((int)a, (int)b, c, false);
#else
  c += (int)(signed char)(a & 0xffu)        * (int)(signed char)(b & 0xffu);
  c += (int)(signed char)((a >> 8) & 0xffu) * (int)(signed char)((b >> 8) & 0xffu);
  c += (int)(signed char)((a >> 16) & 0xffu)* (int)(signed char)((b >> 16) & 0xffu);
  c += (int)(signed char)(a >> 24)          * (int)(signed char)(b >> 24);
  return c;
#endif
}

// round(f*xs) with reference-exact double rounding, clamp, low byte (two's complement)
static __device__ __forceinline__ unsigned q8(float f, float xs) {
  float t = f * xs;        // f32 RNE product, like np (x * x_scale)
  float r = rintf(t);      // round half-to-even, like np.round
  r = fmaxf(-128.0f, fminf(127.0f, r));
  return ((unsigned)(int)r) & 0xffu;
}

// ---------------------------------------------------------------------------
// prep (f32 weights): block 0: w1 = mean|Wk|, ternary-pack Wk -> wk4 flat
//   (wk4[c] byte j = ternary(Wk_flat[c*4+j]), c = p*512 + u, k = u*4 + j).
// block 1: w2 = mean|Wv|, ternary-pack Wv per row (row o word c byte r =
//   ternary(Wv[o][c*4+r])). hdr[0]=w1, hdr[1]=w2.
// ---------------------------------------------------------------------------
__global__ __launch_bounds__(256) void prep_kernel(
    const float* __restrict__ Wk, const float* __restrict__ Wv,
    float* __restrict__ hdr, unsigned* __restrict__ wk4, unsigned* __restrict__ wv4)
{
  __shared__ float red[256];
  __shared__ float s_scale;
  const int tid = threadIdx.x;
  const float* W = (blockIdx.x == 0) ? Wk : Wv;

  float s = 0.f;
  for (int i = 0; i < 128; ++i) s += fabsf(W[tid + i * 256]);
  red[tid] = s;
  __syncthreads();
  for (int o = 128; o > 0; o >>= 1) {
    if (tid < o) red[tid] += red[tid + o];
    __syncthreads();
  }
  if (tid == 0) {
    float sc = fmaxf(red[0] * (1.0f / 32768.0f), 1e-5f);
    s_scale = sc;
    hdr[blockIdx.x] = sc;
  }
  __syncthreads();
  const float sc = s_scale;

  if (blockIdx.x == 0) {
    for (int i = 0; i < 32; ++i) {
      int c = tid + i * 256;               // [0, 8192)
      unsigned pk = 0;
#pragma unroll
      for (int j = 0; j < 4; ++j) {
        float r = rintf(W[c * 4 + j] / sc);
        r = fmaxf(-1.0f, fminf(1.0f, r));
        pk |= (((unsigned)(int)r) & 0xffu) << (8 * j);
      }
      wk4[c] = pk;
    }
  } else {
    for (int i = 0; i < 8; ++i) {
      int o = tid + i * 256;               // output row, [0, 2048)
      unsigned u[4];
#pragma unroll
      for (int c = 0; c < 4; ++c) {
        unsigned pk = 0;
#pragma unroll
        for (int r = 0; r < 4; ++r) {
          float q = rintf(W[o * 16 + c * 4 + r] / sc);
          q = fmaxf(-1.0f, fminf(1.0f, q));
          pk |= (((unsigned)(int)q) & 0xffu) << (8 * r);
        }
        u[c] = pk;
      }
      ((uint4*)wv4)[o] = make_uint4(u[0], u[1], u[2], u[3]);
    }
  }
}

// ---------------------------------------------------------------------------
// kA (f32 x): one wave per 8 tokens. Lane l covers k = 4*(c*64 + l) + j,
// c in 0..7, j in 0..3 (8x float4 coalesced loads / token). absmax ->
// int8 quantize -> 16 rows x 8 sdot4 -> 64-lane butterfly all-reduce ->
// lane-local redundant epilogue (gelu erf, L2 norm * 4, re-quantize).
// Lane 0 writes q2 (16 B, natural p order) + s2 per token.
// ---------------------------------------------------------------------------
__global__ __launch_bounds__(64, 2) void kA(
    const float* __restrict__ x, const float* __restrict__ hdr,
    const unsigned* __restrict__ wk4, uint4* __restrict__ q2w, float* __restrict__ s2w)
{
  const int l = threadIdx.x;
  const long t0 = (long)blockIdx.x * TPW;
  const float w1 = hdr[0], w2 = hdr[1];

  // wk[p][c] = wk4[p*512 + c*64 + l] -> bytes j cover k = 4*(c*64+l)+j
  unsigned wk[16][8];
#pragma unroll
  for (int p = 0; p < 16; ++p)
#pragma unroll
    for (int c = 0; c < 8; ++c) wk[p][c] = wk4[p * 512 + c * 64 + l];

  const float4* xf = (const float4*)x;

  for (int i = 0; i < TPW; ++i) {
    const long tok = t0 + i;

    float4 a[8];
#pragma unroll
    for (int c = 0; c < 8; ++c) a[c] = xf[tok * 512 + c * 64 + l];

    // --- per-token absmax ---
    float mx = 0.0f;
#pragma unroll
    for (int c = 0; c < 8; ++c) {
      mx = fmaxf(mx, fabsf(a[c].x)); mx = fmaxf(mx, fabsf(a[c].y));
      mx = fmaxf(mx, fabsf(a[c].z)); mx = fmaxf(mx, fabsf(a[c].w));
    }
#pragma unroll
    for (int d = 1; d < 64; d <<= 1) mx = fmaxf(mx, __shfl_xor(mx, d, 64));
    const float mcl = fmaxf(mx, 1e-5f);
    const float xs = 127.0f / mcl;   // x_scale
    const float s1 = w1 / xs;        // dequant scale for projection 1

    // --- quantize to packed i8x4 ---
    unsigned qp[8];
#pragma unroll
    for (int c = 0; c < 8; ++c) {
      qp[c] = q8(a[c].x, xs) | (q8(a[c].y, xs) << 8)
            | (q8(a[c].z, xs) << 16) | (q8(a[c].w, xs) << 24);
    }

    // --- 16 integer dot rows (partial over this lane's 32 k's) ---
    int acc[16];
#pragma unroll
    for (int p = 0; p < 16; ++p) {
      int d = 0;
#pragma unroll
      for (int c = 0; c < 8; ++c) d = dot4(qp[c], wk[p][c], d);
      acc[p] = d;
    }

    // --- butterfly all-reduce: every lane gets all 16 totals ---
#pragma unroll
    for (int p = 0; p < 16; ++p) {
#pragma unroll
      for (int d = 1; d < 64; d <<= 1) acc[p] += __shfl_xor(acc[p], d, 64);
    }

    // --- lane-local epilogue (redundant across lanes) ---
    float g[16];
    float ss = 0.0f;
#pragma unroll
    for (int p = 0; p < 16; ++p) {
      float fa = (float)acc[p] * s1;
      float gv = 0.5f * fa * (1.0f + erff(fa * 0.70710678118654752f));
      g[p] = gv;
      ss += gv * gv;
    }
    float rn = fmaxf(sqrtf(ss), 1e-12f);
    float inv = 4.0f / rn;           // * sqrt(P) / norm
    float am = 0.0f;
#pragma unroll
    for (int p = 0; p < 16; ++p) {
      g[p] *= inv;
      am = fmaxf(am, fabsf(g[p]));
    }
    const float mc2 = fmaxf(am, 1e-5f);
    const float xs2 = 127.0f / mc2;
    const float s2 = w2 / xs2;

    unsigned wq[4] = {0u, 0u, 0u, 0u};
#pragma unroll
    for (int p = 0; p < 16; ++p) wq[p >> 2] |= q8(g[p], xs2) << ((p & 3) * 8);

    if (l == 0) {
      q2w[tok] = make_uint4(wq[0], wq[1], wq[2], wq[3]);
      s2w[tok] = s2;
    }
  }
}

// ---------------------------------------------------------------------------
// kB (f32 out): one wave per 8 tokens; Wv ternary rows register-resident
// (lane owns outputs o = m*256 + l*4 + j). q2 word c byte r = p = 4c+r,
// matching wv row pack. 4x sdot4 per output, scale, float4 store.
// ---------------------------------------------------------------------------
__global__ __launch_bounds__(64, 2) void kB(
    const uint4* __restrict__ wv4, const uint4* __restrict__ q2w,
    const float* __restrict__ s2w, float* __restrict__ out)
{
  const int l = threadIdx.x;
  const long t0 = (long)blockIdx.x * TPW;

  uint4 wv[8][4];
#pragma unroll
  for (int m = 0; m < 8; ++m)
#pragma unroll
    for (int j = 0; j < 4; ++j) wv[m][j] = wv4[m * 256 + l * 4 + j];

  for (int i = 0; i < TPW; ++i) {
    const long tok = t0 + i;
    const uint4 q = q2w[tok];
    const float s2 = s2w[tok];
#pragma unroll
    for (int m = 0; m < 8; ++m) {
      float h[4];
#pragma unroll
      for (int j = 0; j < 4; ++j) {
        int d = dot4(q.x, wv[m][j].x, 0);
        d = dot4(q.y, wv[m][j].y, d);
        d = dot4(q.z, wv[m][j].z, d);
        d = dot4(q.w, wv[m][j].w, d);
        h[j] = (float)d * s2;
      }
      *(float4*)(out + (size_t)tok * 2048 + m * 256 + l * 4) =
          make_float4(h[0], h[1], h[2], h[3]);
    }
  }
}

extern "C" void kernel_launch(void* const* d_in, const int* in_sizes, int n_in,
                              void* d_out, int out_size, void* d_ws, size_t ws_size,
                              hipStream_t stream) {
  const float* x  = (const float*)d_in[0];
  const float* Wk = (const float*)d_in[1];
  const float* Wv = (const float*)d_in[2];

  const int tokens = in_sizes[0] / DIN;  // 16384

  char* ws = (char*)d_ws;
  float*    hdr = (float*)(ws + HDR_OFF);
  unsigned* wk4 = (unsigned*)(ws + WK4_OFF);
  unsigned* wv4 = (unsigned*)(ws + WV4_OFF);
  uint4*    q2w = (uint4*)(ws + Q2_OFF);
  float*    s2w = (float*)(ws + Q2_OFF + (size_t)tokens * 16);

  prep_kernel<<<2, 256, 0, stream>>>(Wk, Wv, hdr, wk4, wv4);
  kA<<<tokens / TPW, 64, 0, stream>>>(x, hdr, wk4, q2w, s2w);
  kB<<<tokens / TPW, 64, 0, stream>>>((const uint4*)wv4, q2w, s2w, (float*)d_out);
}

// Round 4
// 254.422 us; speedup vs baseline: 1.0498x; 1.0498x over previous
//
#include <hip/hip_runtime.h>
#include <hip/hip_bf16.h>

#define DIN   2048
#define DOUT  2048
#define NP    16
#define TPW   8   // tokens per wave (kA, kB)

// ws layout (byte offsets)
#define HDR_OFF   0      // 2 floats: w1, w2
#define PART_OFF  64     // 16 floats: per-block abs-sum partials
#define WK4_OFF   256    // 8192 u32 (32 KB) ternary Wk
#define WV4_OFF   (WK4_OFF + 32768)   // 2048 uint4 (32 KB) ternary Wv rows
#define Q2_OFF    (WV4_OFF + 32768)   // tokens * 16 B, then tokens * 4 B scales

static __device__ __forceinline__ int dot4(unsigned a, unsigned b, int c) {
#if defined(__has_builtin) && __has_builtin(__builtin_amdgcn_sdot4)
  return __builtin_amdgcn_sdot4((int)a, (int)b, c, false);
#else
  c += (int)(signed char)(a & 0xffu)        * (int)(signed char)(b & 0xffu);
  c += (int)(signed char)((a >> 8) & 0xffu) * (int)(signed char)((b >> 8) & 0xffu);
  c += (int)(signed char)((a >> 16) & 0xffu)* (int)(signed char)((b >> 16) & 0xffu);
  c += (int)(signed char)(a >> 24)          * (int)(signed char)(b >> 24);
  return c;
#endif
}

// fma-magic int8 quantize: low byte of (f*xs + 1.5*2^23) = round-to-even(f*xs)
// two's complement. Valid because exact absmax bounds |f*xs| <= 127 (no clamp).
static __device__ __forceinline__ unsigned qmagic(float f, float xs) {
  return __float_as_uint(fmaf(f, xs, 12582912.0f)) & 0xffu;
}

// reference-exact double-rounded quantize (used for the 16-value re-quant)
static __device__ __forceinline__ unsigned q8(float f, float xs) {
  float t = f * xs;
  float r = rintf(t);
  r = fmaxf(-128.0f, fminf(127.0f, r));
  return ((unsigned)(int)r) & 0xffu;
}

// ---------------------------------------------------------------------------
// k_reduce: 16 blocks. Blocks 0-7: Wk abs-sum partials; 8-15: Wv.
// Deterministic (no atomics): partials[b] = block's sum.
// ---------------------------------------------------------------------------
__global__ __launch_bounds__(256) void k_reduce(
    const float* __restrict__ Wk, const float* __restrict__ Wv,
    float* __restrict__ partials)
{
  __shared__ float red[256];
  const int tid = threadIdx.x, b = blockIdx.x;
  const float4* W = (const float4*)((b < 8) ? Wk : Wv);
  const int lb = b & 7;

  float s = 0.f;
#pragma unroll
  for (int i = 0; i < 4; ++i) {
    float4 v = W[lb * 1024 + i * 256 + tid];
    s += fabsf(v.x) + fabsf(v.y) + fabsf(v.z) + fabsf(v.w);
  }
  red[tid] = s;
  __syncthreads();
  for (int o = 128; o > 0; o >>= 1) {
    if (tid < o) red[tid] += red[tid + o];
    __syncthreads();
  }
  if (tid == 0) partials[b] = red[0];
}

// ---------------------------------------------------------------------------
// k_pack: 40 blocks. 0-31: ternary-pack Wk (flat: wk4[c] byte j =
// ternary(Wk_flat[4c+j])). 32-39: pack Wv rows (row o word c byte r =
// ternary(Wv[o][4c+r])). Each block recomputes sc from partials (same order
// everywhere -> bitwise identical). Block 0/32 thread 0 writes hdr[0]/hdr[1].
// ---------------------------------------------------------------------------
__global__ __launch_bounds__(256) void k_pack(
    const float* __restrict__ Wk, const float* __restrict__ Wv,
    const float* __restrict__ partials, float* __restrict__ hdr,
    unsigned* __restrict__ wk4, unsigned* __restrict__ wv4)
{
  const int tid = threadIdx.x, b = blockIdx.x;
  const int isV = (b >= 32);
  float sum = 0.f;
#pragma unroll
  for (int i = 0; i < 8; ++i) sum += partials[isV * 8 + i];
  const float sc = fmaxf(sum * (1.0f / 32768.0f), 1e-5f);
  if (tid == 0 && (b == 0 || b == 32)) hdr[isV] = sc;

  if (!isV) {
    const int c = b * 256 + tid;          // [0, 8192)
    float4 w = ((const float4*)Wk)[c];
    unsigned pk = 0;
    const float* wp = &w.x;
#pragma unroll
    for (int j = 0; j < 4; ++j) {
      float r = rintf(wp[j] / sc);
      r = fmaxf(-1.0f, fminf(1.0f, r));
      pk |= (((unsigned)(int)r) & 0xffu) << (8 * j);
    }
    wk4[c] = pk;
  } else {
    const int o = (b - 32) * 256 + tid;   // row [0, 2048)
    unsigned u[4];
#pragma unroll
    for (int c = 0; c < 4; ++c) {
      float4 w = ((const float4*)Wv)[o * 4 + c];
      const float* wp = &w.x;
      unsigned pk = 0;
#pragma unroll
      for (int r = 0; r < 4; ++r) {
        float q = rintf(wp[r] / sc);
        q = fmaxf(-1.0f, fminf(1.0f, q));
        pk |= (((unsigned)(int)q) & 0xffu) << (8 * r);
      }
      u[c] = pk;
    }
    ((uint4*)wv4)[o] = make_uint4(u[0], u[1], u[2], u[3]);
  }
}

// ---------------------------------------------------------------------------
// kA: one wave per 8 tokens. Per token: absmax -> fma-magic int8 quantize ->
// 16 rows x 8 sdot4 -> 4-stage identity-perm reduce-scatter (lane ends with
// partial for p = l&15, summed over lane bits 0..3). Every 4 tokens: route
// token slots over lane bits 4/5 (group g = l>>4 owns token base+g), then a
// single group-local epilogue: 1 erff/lane, 16-lane reductions for L2 norm
// and absmax, reference-exact re-quant, 5-shfl byte pack. Lane l&15==0 of
// each group writes its token's q2 (16 B) + s2.
// ---------------------------------------------------------------------------
__global__ __launch_bounds__(64, 2) void kA(
    const float* __restrict__ x, const float* __restrict__ hdr,
    const unsigned* __restrict__ wk4, uint4* __restrict__ q2w, float* __restrict__ s2w)
{
  const int l = threadIdx.x;
  const long t0 = (long)blockIdx.x * TPW;
  const float w1 = hdr[0], w2 = hdr[1];

  // wk[p][c] = wk4[p*512 + c*64 + l] -> bytes j cover k = 4*(c*64+l)+j
  unsigned wk[16][8];
#pragma unroll
  for (int p = 0; p < 16; ++p)
#pragma unroll
    for (int c = 0; c < 8; ++c) wk[p][c] = wk4[p * 512 + c * 64 + l];

  const float4* xf = (const float4*)x;

  int   svi[4];   // reduce-scattered partial per token slot
  float s1v[4];   // dequant scale per token slot

  for (int i = 0; i < TPW; ++i) {
    const long tok = t0 + i;

    float4 a[8];
#pragma unroll
    for (int c = 0; c < 8; ++c) a[c] = xf[tok * 512 + c * 64 + l];

    // --- per-token absmax (full wave) ---
    float mx = 0.0f;
#pragma unroll
    for (int c = 0; c < 8; ++c) {
      mx = fmaxf(mx, fabsf(a[c].x)); mx = fmaxf(mx, fabsf(a[c].y));
      mx = fmaxf(mx, fabsf(a[c].z)); mx = fmaxf(mx, fabsf(a[c].w));
    }
#pragma unroll
    for (int d = 1; d < 64; d <<= 1) mx = fmaxf(mx, __shfl_xor(mx, d, 64));
    const float mcl = fmaxf(mx, 1e-5f);
    const float xs = 127.0f / mcl;
    s1v[i & 3] = w1 / xs;

    // --- quantize to packed i8x4 (no clamp needed: |f*xs| <= 127 exactly) ---
    unsigned qp[8];
#pragma unroll
    for (int c = 0; c < 8; ++c) {
      qp[c] = qmagic(a[c].x, xs) | (qmagic(a[c].y, xs) << 8)
            | (qmagic(a[c].z, xs) << 16) | (qmagic(a[c].w, xs) << 24);
    }

    // --- 16 integer dot rows (partial over this lane's 32 k's) ---
    int acc[16];
#pragma unroll
    for (int p = 0; p < 16; ++p) {
      int d = 0;
#pragma unroll
      for (int c = 0; c < 8; ++c) d = dot4(qp[c], wk[p][c], d);
      acc[p] = d;
    }

    // --- recursive-halving reduce-scatter, identity perm (p = l&15) ---
    // Invariant after stage b: acc[j] holds partial for
    //   p = (j << (b+1)) | (l & ((2<<b)-1)), summed over lane bits 0..b.
#pragma unroll
    for (int b = 0; b < 4; ++b) {
      const int lb = (l >> b) & 1;
#pragma unroll
      for (int j = 0; j < 8; ++j) {
        if (j < (8 >> b)) {
          int keep = lb ? acc[2 * j + 1] : acc[2 * j];
          int send = lb ? acc[2 * j]     : acc[2 * j + 1];
          acc[j] = keep + __shfl_xor(send, 1 << b, 64);
        }
      }
    }
    svi[i & 3] = acc[0];

    if ((i & 3) == 3) {
      // --- route 4 token slots over lane bits 4/5: group g owns slot g ---
      const int lb4 = (l >> 4) & 1, lb5 = (l >> 5) & 1;
      int r0 = (lb4 ? svi[1] : svi[0]) + __shfl_xor(lb4 ? svi[0] : svi[1], 16, 64);
      int r1 = (lb4 ? svi[3] : svi[2]) + __shfl_xor(lb4 ? svi[2] : svi[3], 16, 64);
      int rr = (lb5 ? r1 : r0) + __shfl_xor(lb5 ? r0 : r1, 32, 64);
      float s1a = lb4 ? s1v[1] : s1v[0];
      float s1b = lb4 ? s1v[3] : s1v[2];
      const float s1sel = lb5 ? s1b : s1a;

      // --- group-local epilogue: token = t0 + (i&~3) + (l>>4), p = l&15 ---
      const float fa = (float)rr * s1sel;
      const float gv = 0.5f * fa * (1.0f + erff(fa * 0.70710678118654752f));
      float ss = gv * gv;
      ss += __shfl_xor(ss, 1, 64); ss += __shfl_xor(ss, 2, 64);
      ss += __shfl_xor(ss, 4, 64); ss += __shfl_xor(ss, 8, 64);
      const float rn = fmaxf(sqrtf(ss), 1e-12f);
      const float gn = gv * (4.0f / rn);
      float am = fabsf(gn);
      {
        float o;
        o = __shfl_xor(am, 1, 64); am = fmaxf(am, o);
        o = __shfl_xor(am, 2, 64); am = fmaxf(am, o);
        o = __shfl_xor(am, 4, 64); am = fmaxf(am, o);
        o = __shfl_xor(am, 8, 64); am = fmaxf(am, o);
      }
      const float mc2 = fmaxf(am, 1e-5f);
      const float xs2 = 127.0f / mc2;
      const float s2 = w2 / xs2;

      unsigned sh = q8(gn, xs2) << ((l & 3) * 8);
      sh |= (unsigned)__shfl_xor((int)sh, 1, 64);
      sh |= (unsigned)__shfl_xor((int)sh, 2, 64);
      const unsigned wa = (unsigned)__shfl_xor((int)sh, 4, 64);
      const unsigned wb = (unsigned)__shfl_xor((int)sh, 8, 64);
      const unsigned wc = (unsigned)__shfl_xor((int)sh, 12, 64);
      if ((l & 15) == 0) {
        const long tk = t0 + (i & ~3) + (l >> 4);
        q2w[tk] = make_uint4(sh, wa, wb, wc);
        s2w[tk] = s2;
      }
    }
  }
}

// ---------------------------------------------------------------------------
// kB: one wave per 8 tokens; Wv ternary rows register-resident (lane owns
// outputs o = m*256 + l*4 + j). 4x sdot4 per output, scale, float4 store.
// ---------------------------------------------------------------------------
__global__ __launch_bounds__(64, 2) void kB(
    const uint4* __restrict__ wv4, const uint4* __restrict__ q2w,
    const float* __restrict__ s2w, float* __restrict__ out)
{
  const int l = threadIdx.x;
  const long t0 = (long)blockIdx.x * TPW;

  uint4 wv[8][4];
#pragma unroll
  for (int m = 0; m < 8; ++m)
#pragma unroll
    for (int j = 0; j < 4; ++j) wv[m][j] = wv4[m * 256 + l * 4 + j];

  for (int i = 0; i < TPW; ++i) {
    const long tok = t0 + i;
    const uint4 q = q2w[tok];
    const float s2 = s2w[tok];
#pragma unroll
    for (int m = 0; m < 8; ++m) {
      float h[4];
#pragma unroll
      for (int j = 0; j < 4; ++j) {
        int d = dot4(q.x, wv[m][j].x, 0);
        d = dot4(q.y, wv[m][j].y, d);
        d = dot4(q.z, wv[m][j].z, d);
        d = dot4(q.w, wv[m][j].w, d);
        h[j] = (float)d * s2;
      }
      *(float4*)(out + (size_t)tok * 2048 + m * 256 + l * 4) =
          make_float4(h[0], h[1], h[2], h[3]);
    }
  }
}

extern "C" void kernel_launch(void* const* d_in, const int* in_sizes, int n_in,
                              void* d_out, int out_size, void* d_ws, size_t ws_size,
                              hipStream_t stream) {
  const float* x  = (const float*)d_in[0];
  const float* Wk = (const float*)d_in[1];
  const float* Wv = (const float*)d_in[2];

  const int tokens = in_sizes[0] / DIN;  // 16384

  char* ws = (char*)d_ws;
  float*    hdr  = (float*)(ws + HDR_OFF);
  float*    part = (float*)(ws + PART_OFF);
  unsigned* wk4  = (unsigned*)(ws + WK4_OFF);
  unsigned* wv4  = (unsigned*)(ws + WV4_OFF);
  uint4*    q2w  = (uint4*)(ws + Q2_OFF);
  float*    s2w  = (float*)(ws + Q2_OFF + (size_t)tokens * 16);

  k_reduce<<<16, 256, 0, stream>>>(Wk, Wv, part);
  k_pack<<<40, 256, 0, stream>>>(Wk, Wv, part, hdr, wk4, wv4);
  kA<<<tokens / TPW, 64, 0, stream>>>(x, hdr, wk4, q2w, s2w);
  kB<<<tokens / TPW, 64, 0, stream>>>((const uint4*)wv4, q2w, s2w, (float*)d_out);
}